// Round 3
// baseline (256.139 us; speedup 1.0000x reference)
//
#include <hip/hip_runtime.h>
#include <hip/hip_bf16.h>

// RBDispatcher: fused double-gather + concat (pure data movement, HBM-bound).
//   out[0 .. n_s2)         = x[ idx_s1[ idx_s2[r] ] / top_k ]
//   out[n_s2 .. n_s2+n_s1) = x[ idx_s1[r - n_s2] / top_k ]
//
// R3: wave handles TWO consecutive rows. indices_s1 is sorted, so s1-section
// row pairs usually share the same src row (top_k=2) -> load the 8KB row into
// registers ONCE, store twice. Full-row register staging gives 8 outstanding
// 1KiB loads/wave. NT stores keep `out` (192 MiB stream) out of the LLC so
// the 64 MiB `x` stays resident. XCD swizzle gives each XCD a contiguous
// sorted src range.

typedef float v4f __attribute__((ext_vector_type(4)));

__global__ __launch_bounds__(256) void rb_dispatch_kernel(
    const float* __restrict__ x,
    const int* __restrict__ idx_s1,
    const int* __restrict__ idx_s2,
    const int* __restrict__ top_k_ptr,
    float* __restrict__ out,
    int n_s2, int n_rows, int n_blocks, int nvec /* d/4 */) {
  // XCD swizzle: blocks round-robin across 8 XCDs; remap so XCD j gets a
  // contiguous block range (contiguous rows -> contiguous sorted srcs in L2).
  const int b = blockIdx.x;
  const int v = (b & 7) * (n_blocks >> 3) + (b >> 3);

  const int wave = threadIdx.x >> 6;
  const int lane = threadIdx.x & 63;
  const int r0 = v * 8 + wave * 2;   // 4 waves/block x 2 rows/wave
  const int r1 = r0 + 1;
  if (r0 >= n_rows) return;

  const int top_k = *top_k_ptr;

  // Wave-uniform src computation (scalar loads).
  int s0, s1;
  if (r0 < n_s2) s0 = idx_s1[idx_s2[r0]] / top_k;
  else           s0 = idx_s1[r0 - n_s2] / top_k;
  if (r1 < n_s2) s1 = idx_s1[idx_s2[r1]] / top_k;
  else           s1 = idx_s1[r1 - n_s2] / top_k;

  if (nvec == 512) {  // d=2048 fast path: 8 float4 per lane = full row/wave
    const v4f* __restrict__ sp0 = (const v4f*)x + (size_t)s0 * 512;
    v4f* __restrict__ dp0 = (v4f*)out + (size_t)r0 * 512;
    v4f* __restrict__ dp1 = (v4f*)out + (size_t)r1 * 512;

    v4f r[8];
    #pragma unroll
    for (int k = 0; k < 8; ++k) r[k] = sp0[lane + 64 * k];   // 8 loads in flight
    #pragma unroll
    for (int k = 0; k < 8; ++k)
      __builtin_nontemporal_store(r[k], dp0 + lane + 64 * k);

    if (s1 == s0) {       // sorted-pair dedup: reuse registers, skip the load
      #pragma unroll
      for (int k = 0; k < 8; ++k)
        __builtin_nontemporal_store(r[k], dp1 + lane + 64 * k);
    } else {
      const v4f* __restrict__ sp1 = (const v4f*)x + (size_t)s1 * 512;
      #pragma unroll
      for (int k = 0; k < 8; ++k) r[k] = sp1[lane + 64 * k];
      #pragma unroll
      for (int k = 0; k < 8; ++k)
        __builtin_nontemporal_store(r[k], dp1 + lane + 64 * k);
    }
  } else {  // generic fallback
    const v4f* sp0 = (const v4f*)x + (size_t)s0 * nvec;
    const v4f* sp1 = (const v4f*)x + (size_t)s1 * nvec;
    v4f* dp0 = (v4f*)out + (size_t)r0 * nvec;
    v4f* dp1 = (v4f*)out + (size_t)r1 * nvec;
    for (int i = lane; i < nvec; i += 64) {
      __builtin_nontemporal_store(sp0[i], dp0 + i);
      __builtin_nontemporal_store(sp1[i], dp1 + i);
    }
  }
}

extern "C" void kernel_launch(void* const* d_in, const int* in_sizes, int n_in,
                              void* d_out, int out_size, void* d_ws, size_t ws_size,
                              hipStream_t stream) {
  const float* x      = (const float*)d_in[0];
  const int*   idx_s1 = (const int*)d_in[1];
  const int*   idx_s2 = (const int*)d_in[2];
  // d_in[3] = n_tokens (unused), d_in[4] = top_k (device scalar)
  const int*   top_k  = (const int*)d_in[4];
  float*       out    = (float*)d_out;

  const int n_s1   = in_sizes[1];       // 16384
  const int n_s2   = in_sizes[2];       // 8192
  const int n_rows = n_s1 + n_s2;       // 24576
  const int d      = out_size / n_rows; // 2048
  const int nvec   = d / 4;             // 512

  // 4 waves/block, 2 rows/wave -> 8 rows/block.
  const int n_blocks = (n_rows + 7) / 8;  // 3072 (multiple of 8 for swizzle)

  rb_dispatch_kernel<<<n_blocks, 256, 0, stream>>>(
      x, idx_s1, idx_s2, top_k, out, n_s2, n_rows, n_blocks, nvec);
}